// Round 2
// baseline (586.793 us; speedup 1.0000x reference)
//
#include <hip/hip_runtime.h>

#define KC 64   // clusters
#define DD 64   // dims

// ws layout (floats): [0..63] colsum, [64..127] distsum, [128..191] counts, [192] sep_sum

// 4 lanes per row: lane owns 16 columns (4x float4). 16 rows per wave-iteration.
// Cross-iteration DOUBLE-BUFFER: next group's assign+z are prefetched at the top
// of the loop, current group is computed entirely from registers. This keeps all
// 8 global loads per wave in flight together (vs compiler-staggered at VGPR=40).
__global__ __launch_bounds__(256, 6) void aux_main(
    const float* __restrict__ z,
    const float* __restrict__ assign,
    const float* __restrict__ centers,
    float* __restrict__ ws, int B)
{
    __shared__ float4 s_c4[KC * DD / 4];   // centers, XOR-swizzled, 16 KB
    __shared__ float s_colsum[KC];
    __shared__ float s_dist[KC];
    __shared__ float s_cnt[KC];

    const int tid = threadIdx.x;

    // stage centers with XOR swizzle: row k, float4 c -> slot (c ^ (k&7))
    {
        const float4* c4 = (const float4*)centers;
        for (int i = tid; i < KC * DD / 4; i += 256) {
            int k = i >> 4, c = i & 15;
            s_c4[(k << 4) | (c ^ (k & 7))] = c4[i];
        }
    }
    if (tid < KC) { s_colsum[tid] = 0.f; s_dist[tid] = 0.f; s_cnt[tid] = 0.f; }
    __syncthreads();

    const int wave = tid >> 6;
    const int lane = tid & 63;
    const int row4 = lane >> 2;   // 0..15 : which row of the 16-row group
    const int qd   = lane & 3;    // 0..3  : which 16-col quarter

    const int gw   = blockIdx.x * 4 + wave;
    const int nw   = gridDim.x * 4;
    const int ngrp = (B + 15) >> 4;

    const float4* ap = (const float4*)assign;
    const float4* zp = (const float4*)z;

    float4 cs0 = {0,0,0,0}, cs1 = {0,0,0,0}, cs2 = {0,0,0,0}, cs3 = {0,0,0,0};

    // clamped float4-index for group g (rows clamped into the buffer; results
    // from clamped rows are never accumulated)
    #define GOFF(gg) ({ int _r = (gg) * 16 + row4; if (_r >= B) _r = B - 1; \
                        ((size_t)_r << 4) + qd; })

    // ---- prologue: load group gw ----
    int g = gw;
    {
        int gc = (g < ngrp) ? g : (ngrp - 1);
        size_t off = GOFF(gc);
        // fall through to loop with these in a*/z*
        // (waves with no work still do one clamped, unused load)
        // current-buffer registers:
        // a0..a3, z0..z3 declared below
    }
    size_t off0 = GOFF((g < ngrp) ? g : (ngrp - 1));
    float4 a0 = ap[off0], a1 = ap[off0 + 4], a2 = ap[off0 + 8], a3 = ap[off0 + 12];
    float4 z0 = zp[off0], z1 = zp[off0 + 4], z2 = zp[off0 + 8], z3 = zp[off0 + 12];

    for (; g < ngrp; g += nw) {
        // ---- prefetch next group ----
        int gn = g + nw; if (gn >= ngrp) gn = ngrp - 1;
        size_t noff = GOFF(gn);
        float4 na0 = ap[noff], na1 = ap[noff + 4], na2 = ap[noff + 8], na3 = ap[noff + 12];
        float4 nz0 = zp[noff], nz1 = zp[noff + 4], nz2 = zp[noff + 8], nz3 = zp[noff + 12];
        // pin issue order: all 8 prefetch loads issue before the compute below
        asm volatile("" ::: "memory");

        const int r = g * 16 + row4;
        if (r < B) {
            cs0.x += a0.x; cs0.y += a0.y; cs0.z += a0.z; cs0.w += a0.w;
            cs1.x += a1.x; cs1.y += a1.y; cs1.z += a1.z; cs1.w += a1.w;
            cs2.x += a2.x; cs2.y += a2.y; cs2.z += a2.z; cs2.w += a2.w;
            cs3.x += a3.x; cs3.y += a3.y; cs3.z += a3.z; cs3.w += a3.w;

            // in-lane argmax over 16 values, increasing column order (ties -> lowest)
            const int cb0 = qd * 4;
            float m = a0.x; int mi = cb0;
            #define CAND(v, c) if ((v) > m) { m = (v); mi = (c); }
            CAND(a0.y, cb0 + 1)  CAND(a0.z, cb0 + 2)  CAND(a0.w, cb0 + 3)
            CAND(a1.x, 16 + cb0) CAND(a1.y, 17 + cb0) CAND(a1.z, 18 + cb0) CAND(a1.w, 19 + cb0)
            CAND(a2.x, 32 + cb0) CAND(a2.y, 33 + cb0) CAND(a2.z, 34 + cb0) CAND(a2.w, 35 + cb0)
            CAND(a3.x, 48 + cb0) CAND(a3.y, 49 + cb0) CAND(a3.z, 50 + cb0) CAND(a3.w, 51 + cb0)
            #undef CAND

            // reduce across the 4 lanes of this row; ties -> lowest col
            #pragma unroll
            for (int d = 1; d < 4; d <<= 1) {
                float om  = __shfl_xor(m, d, 4);
                int   omi = __shfl_xor(mi, d, 4);
                if (om > m || (om == m && omi < mi)) { m = om; mi = omi; }
            }
            const int hard = mi;

            // gather this row's center columns from swizzled LDS
            const float4* cb = s_c4 + (hard << 4);
            const int sw = hard & 7;
            float4 c0 = cb[(qd +  0) ^ sw];
            float4 c1 = cb[(qd +  4) ^ sw];
            float4 c2 = cb[(qd +  8) ^ sw];
            float4 c3 = cb[(qd + 12) ^ sw];

            float d0, ss = 0.f;
            d0 = z0.x - c0.x; ss += d0 * d0;  d0 = z0.y - c0.y; ss += d0 * d0;
            d0 = z0.z - c0.z; ss += d0 * d0;  d0 = z0.w - c0.w; ss += d0 * d0;
            d0 = z1.x - c1.x; ss += d0 * d0;  d0 = z1.y - c1.y; ss += d0 * d0;
            d0 = z1.z - c1.z; ss += d0 * d0;  d0 = z1.w - c1.w; ss += d0 * d0;
            d0 = z2.x - c2.x; ss += d0 * d0;  d0 = z2.y - c2.y; ss += d0 * d0;
            d0 = z2.z - c2.z; ss += d0 * d0;  d0 = z2.w - c2.w; ss += d0 * d0;
            d0 = z3.x - c3.x; ss += d0 * d0;  d0 = z3.y - c3.y; ss += d0 * d0;
            d0 = z3.z - c3.z; ss += d0 * d0;  d0 = z3.w - c3.w; ss += d0 * d0;

            ss += __shfl_xor(ss, 1, 4);
            ss += __shfl_xor(ss, 2, 4);

            if (qd == 0) {
                atomicAdd(&s_dist[hard], ss > 0.f ? sqrtf(ss) : 0.f);
                atomicAdd(&s_cnt[hard], 1.f);
            }
        }

        // ---- swap buffers ----
        a0 = na0; a1 = na1; a2 = na2; a3 = na3;
        z0 = nz0; z1 = nz1; z2 = nz2; z3 = nz3;
    }
    #undef GOFF

    // reduce column sums across the 16 lanes sharing each qd (strides 4..32)
    #pragma unroll
    for (int d = 4; d < 64; d <<= 1) {
        cs0.x += __shfl_xor(cs0.x, d); cs0.y += __shfl_xor(cs0.y, d);
        cs0.z += __shfl_xor(cs0.z, d); cs0.w += __shfl_xor(cs0.w, d);
        cs1.x += __shfl_xor(cs1.x, d); cs1.y += __shfl_xor(cs1.y, d);
        cs1.z += __shfl_xor(cs1.z, d); cs1.w += __shfl_xor(cs1.w, d);
        cs2.x += __shfl_xor(cs2.x, d); cs2.y += __shfl_xor(cs2.y, d);
        cs2.z += __shfl_xor(cs2.z, d); cs2.w += __shfl_xor(cs2.w, d);
        cs3.x += __shfl_xor(cs3.x, d); cs3.y += __shfl_xor(cs3.y, d);
        cs3.z += __shfl_xor(cs3.z, d); cs3.w += __shfl_xor(cs3.w, d);
    }
    if (lane < 4) {
        const int b = lane * 4;
        atomicAdd(&s_colsum[ 0 + b + 0], cs0.x); atomicAdd(&s_colsum[ 0 + b + 1], cs0.y);
        atomicAdd(&s_colsum[ 0 + b + 2], cs0.z); atomicAdd(&s_colsum[ 0 + b + 3], cs0.w);
        atomicAdd(&s_colsum[16 + b + 0], cs1.x); atomicAdd(&s_colsum[16 + b + 1], cs1.y);
        atomicAdd(&s_colsum[16 + b + 2], cs1.z); atomicAdd(&s_colsum[16 + b + 3], cs1.w);
        atomicAdd(&s_colsum[32 + b + 0], cs2.x); atomicAdd(&s_colsum[32 + b + 1], cs2.y);
        atomicAdd(&s_colsum[32 + b + 2], cs2.z); atomicAdd(&s_colsum[32 + b + 3], cs2.w);
        atomicAdd(&s_colsum[48 + b + 0], cs3.x); atomicAdd(&s_colsum[48 + b + 1], cs3.y);
        atomicAdd(&s_colsum[48 + b + 2], cs3.z); atomicAdd(&s_colsum[48 + b + 3], cs3.w);
    }
    __syncthreads();

    if (tid < KC) {
        atomicAdd(&ws[tid],       s_colsum[tid]);
        atomicAdd(&ws[64 + tid],  s_dist[tid]);
        atomicAdd(&ws[128 + tid], s_cnt[tid]);
    }
}

// one block per center row i; thread j computes ||c_i - c_j|| (j != i)
__global__ void aux_sep(const float* __restrict__ centers, float* __restrict__ ws)
{
    __shared__ float rowi[DD];
    const int i = blockIdx.x;
    const int j = threadIdx.x;

    if (j < 16) ((float4*)rowi)[j] = ((const float4*)(centers + (size_t)i * DD))[j];
    __syncthreads();

    float ss = 0.f;
    const float4* cj = (const float4*)(centers + (size_t)j * DD);
    #pragma unroll
    for (int q = 0; q < 16; q++) {
        float4 u = cj[q];
        float e0 = u.x - rowi[q*4+0], e1 = u.y - rowi[q*4+1];
        float e2 = u.z - rowi[q*4+2], e3 = u.w - rowi[q*4+3];
        ss += e0*e0 + e1*e1 + e2*e2 + e3*e3;
    }
    float dist = (i != j && ss > 0.f) ? sqrtf(ss) : 0.f;

    #pragma unroll
    for (int d = 1; d < 64; d <<= 1) dist += __shfl_xor(dist, d, 64);
    if (j == 0) atomicAdd(&ws[192], dist);
}

__global__ void aux_fin(const float* __restrict__ ws, float* __restrict__ out, int B)
{
    const int k = threadIdx.x;  // 64 threads
    const float uni = 1.0f / 64.0f;

    float p   = ws[k] / (float)B;
    float bal = uni * (logf(uni) - logf(p + 1e-8f));

    float cnt = ws[128 + k];
    float ne  = cnt > 0.f ? 1.f : 0.f;
    float pcm = ne * (ws[64 + k] / fmaxf(cnt, 1.f));
    float ps  = p;

    #pragma unroll
    for (int d = 1; d < 64; d <<= 1) {
        bal += __shfl_xor(bal, d, 64);
        ne  += __shfl_xor(ne,  d, 64);
        pcm += __shfl_xor(pcm, d, 64);
        ps  += __shfl_xor(ps,  d, 64);
    }

    float comp = pcm / fmaxf(ne, 1.f);
    float pm   = ps * (1.0f / 64.0f);
    float dv   = (p - pm) * (p - pm);
    #pragma unroll
    for (int d = 1; d < 64; d <<= 1) dv += __shfl_xor(dv, d, 64);
    float stdv = sqrtf(dv / 63.0f);

    float sep = -ws[192] / (64.0f * 63.0f);

    if (k == 0) {
        out[0] = 0.1f * bal + 0.1f * sep + 0.1f * comp;
        out[1] = bal;
        out[2] = sep;
        out[3] = comp;
        out[4] = stdv;
    }
}

extern "C" void kernel_launch(void* const* d_in, const int* in_sizes, int n_in,
                              void* d_out, int out_size, void* d_ws, size_t ws_size,
                              hipStream_t stream) {
    const float* z       = (const float*)d_in[0];
    const float* assign  = (const float*)d_in[1];
    const float* centers = (const float*)d_in[2];
    float* ws = (float*)d_ws;
    const int B = in_sizes[0] / DD;

    hipMemsetAsync(d_ws, 0, 1024, stream);
    aux_sep<<<64, 64, 0, stream>>>(centers, ws);
    aux_main<<<2048, 256, 0, stream>>>(z, assign, centers, ws, B);
    aux_fin<<<1, 64, 0, stream>>>(ws, (float*)d_out, B);
}

// Round 3
// 490.657 us; speedup vs baseline: 1.1959x; 1.1959x over previous
//
#include <hip/hip_runtime.h>

#define KC 64   // clusters
#define DD 64   // dims

// ws layout (floats): [0..63] colsum, [64..127] distsum, [128..191] counts, [192] sep_sum

// 4 lanes per row: lane owns 16 columns (4x float4). 16 rows per wave-iteration.
// Cross-iteration register DOUBLE-BUFFER (8 float4 in flight across the whole body).
// __launch_bounds__(256,4): VGPR cap 128 — the ~110-reg peak live set MUST fit
// without spilling (R2 post-mortem: cap 85 spilled the prefetch buffer to scratch,
// WRITE_SIZE 374 MB).
__global__ __launch_bounds__(256, 4) void aux_main(
    const float* __restrict__ z,
    const float* __restrict__ assign,
    const float* __restrict__ centers,
    float* __restrict__ ws, int B)
{
    __shared__ float4 s_c4[KC * DD / 4];   // centers, XOR-swizzled, 16 KB
    __shared__ float s_colsum[KC];
    __shared__ float s_dist[KC];
    __shared__ float s_cnt[KC];

    const int tid = threadIdx.x;

    // stage centers with XOR swizzle: row k, float4 c -> slot (c ^ (k&7))
    {
        const float4* c4 = (const float4*)centers;
        for (int i = tid; i < KC * DD / 4; i += 256) {
            int k = i >> 4, c = i & 15;
            s_c4[(k << 4) | (c ^ (k & 7))] = c4[i];
        }
    }
    if (tid < KC) { s_colsum[tid] = 0.f; s_dist[tid] = 0.f; s_cnt[tid] = 0.f; }
    __syncthreads();

    const int wave = tid >> 6;
    const int lane = tid & 63;
    const int row4 = lane >> 2;   // 0..15 : which row of the 16-row group
    const int qd   = lane & 3;    // 0..3  : which 16-col quarter

    const int gw   = blockIdx.x * 4 + wave;
    const int nw   = gridDim.x * 4;
    const int ngrp = (B + 15) >> 4;

    const float4* ap = (const float4*)assign;
    const float4* zp = (const float4*)z;

    float4 cs0 = {0,0,0,0}, cs1 = {0,0,0,0}, cs2 = {0,0,0,0}, cs3 = {0,0,0,0};

    // clamped float4-index for group g (clamped rows' results never accumulated)
    #define GOFF(gg) ({ int _r = (gg) * 16 + row4; if (_r >= B) _r = B - 1; \
                        ((size_t)_r << 4) + qd; })

    int g = gw;
    size_t off0 = GOFF((g < ngrp) ? g : (ngrp - 1));
    float4 a0 = ap[off0], a1 = ap[off0 + 4], a2 = ap[off0 + 8], a3 = ap[off0 + 12];
    float4 z0 = zp[off0], z1 = zp[off0 + 4], z2 = zp[off0 + 8], z3 = zp[off0 + 12];

    for (; g < ngrp; g += nw) {
        // ---- prefetch next group (all 8 loads in flight across the body) ----
        int gn = g + nw; if (gn >= ngrp) gn = ngrp - 1;
        size_t noff = GOFF(gn);
        float4 na0 = ap[noff], na1 = ap[noff + 4], na2 = ap[noff + 8], na3 = ap[noff + 12];
        float4 nz0 = zp[noff], nz1 = zp[noff + 4], nz2 = zp[noff + 8], nz3 = zp[noff + 12];
        asm volatile("" ::: "memory");   // pin: prefetch issues before body compute

        const int r = g * 16 + row4;
        if (r < B) {
            cs0.x += a0.x; cs0.y += a0.y; cs0.z += a0.z; cs0.w += a0.w;
            cs1.x += a1.x; cs1.y += a1.y; cs1.z += a1.z; cs1.w += a1.w;
            cs2.x += a2.x; cs2.y += a2.y; cs2.z += a2.z; cs2.w += a2.w;
            cs3.x += a3.x; cs3.y += a3.y; cs3.z += a3.z; cs3.w += a3.w;

            // in-lane argmax over 16 values, increasing column order (ties -> lowest)
            const int cb0 = qd * 4;
            float m = a0.x; int mi = cb0;
            #define CAND(v, c) if ((v) > m) { m = (v); mi = (c); }
            CAND(a0.y, cb0 + 1)  CAND(a0.z, cb0 + 2)  CAND(a0.w, cb0 + 3)
            CAND(a1.x, 16 + cb0) CAND(a1.y, 17 + cb0) CAND(a1.z, 18 + cb0) CAND(a1.w, 19 + cb0)
            CAND(a2.x, 32 + cb0) CAND(a2.y, 33 + cb0) CAND(a2.z, 34 + cb0) CAND(a2.w, 35 + cb0)
            CAND(a3.x, 48 + cb0) CAND(a3.y, 49 + cb0) CAND(a3.z, 50 + cb0) CAND(a3.w, 51 + cb0)
            #undef CAND

            // reduce across the 4 lanes of this row; ties -> lowest col
            #pragma unroll
            for (int d = 1; d < 4; d <<= 1) {
                float om  = __shfl_xor(m, d, 4);
                int   omi = __shfl_xor(mi, d, 4);
                if (om > m || (om == m && omi < mi)) { m = om; mi = omi; }
            }
            const int hard = mi;

            // gather this row's center columns from swizzled LDS
            const float4* cb = s_c4 + (hard << 4);
            const int sw = hard & 7;
            float4 c0 = cb[(qd +  0) ^ sw];
            float4 c1 = cb[(qd +  4) ^ sw];
            float4 c2 = cb[(qd +  8) ^ sw];
            float4 c3 = cb[(qd + 12) ^ sw];

            float d0, ss = 0.f;
            d0 = z0.x - c0.x; ss += d0 * d0;  d0 = z0.y - c0.y; ss += d0 * d0;
            d0 = z0.z - c0.z; ss += d0 * d0;  d0 = z0.w - c0.w; ss += d0 * d0;
            d0 = z1.x - c1.x; ss += d0 * d0;  d0 = z1.y - c1.y; ss += d0 * d0;
            d0 = z1.z - c1.z; ss += d0 * d0;  d0 = z1.w - c1.w; ss += d0 * d0;
            d0 = z2.x - c2.x; ss += d0 * d0;  d0 = z2.y - c2.y; ss += d0 * d0;
            d0 = z2.z - c2.z; ss += d0 * d0;  d0 = z2.w - c2.w; ss += d0 * d0;
            d0 = z3.x - c3.x; ss += d0 * d0;  d0 = z3.y - c3.y; ss += d0 * d0;
            d0 = z3.z - c3.z; ss += d0 * d0;  d0 = z3.w - c3.w; ss += d0 * d0;

            ss += __shfl_xor(ss, 1, 4);
            ss += __shfl_xor(ss, 2, 4);

            if (qd == 0) {
                atomicAdd(&s_dist[hard], ss > 0.f ? sqrtf(ss) : 0.f);
                atomicAdd(&s_cnt[hard], 1.f);
            }
        }

        // ---- swap buffers ----
        a0 = na0; a1 = na1; a2 = na2; a3 = na3;
        z0 = nz0; z1 = nz1; z2 = nz2; z3 = nz3;
    }
    #undef GOFF

    // reduce column sums across the 16 lanes sharing each qd (strides 4..32)
    #pragma unroll
    for (int d = 4; d < 64; d <<= 1) {
        cs0.x += __shfl_xor(cs0.x, d); cs0.y += __shfl_xor(cs0.y, d);
        cs0.z += __shfl_xor(cs0.z, d); cs0.w += __shfl_xor(cs0.w, d);
        cs1.x += __shfl_xor(cs1.x, d); cs1.y += __shfl_xor(cs1.y, d);
        cs1.z += __shfl_xor(cs1.z, d); cs1.w += __shfl_xor(cs1.w, d);
        cs2.x += __shfl_xor(cs2.x, d); cs2.y += __shfl_xor(cs2.y, d);
        cs2.z += __shfl_xor(cs2.z, d); cs2.w += __shfl_xor(cs2.w, d);
        cs3.x += __shfl_xor(cs3.x, d); cs3.y += __shfl_xor(cs3.y, d);
        cs3.z += __shfl_xor(cs3.z, d); cs3.w += __shfl_xor(cs3.w, d);
    }
    if (lane < 4) {
        const int b = lane * 4;
        atomicAdd(&s_colsum[ 0 + b + 0], cs0.x); atomicAdd(&s_colsum[ 0 + b + 1], cs0.y);
        atomicAdd(&s_colsum[ 0 + b + 2], cs0.z); atomicAdd(&s_colsum[ 0 + b + 3], cs0.w);
        atomicAdd(&s_colsum[16 + b + 0], cs1.x); atomicAdd(&s_colsum[16 + b + 1], cs1.y);
        atomicAdd(&s_colsum[16 + b + 2], cs1.z); atomicAdd(&s_colsum[16 + b + 3], cs1.w);
        atomicAdd(&s_colsum[32 + b + 0], cs2.x); atomicAdd(&s_colsum[32 + b + 1], cs2.y);
        atomicAdd(&s_colsum[32 + b + 2], cs2.z); atomicAdd(&s_colsum[32 + b + 3], cs2.w);
        atomicAdd(&s_colsum[48 + b + 0], cs3.x); atomicAdd(&s_colsum[48 + b + 1], cs3.y);
        atomicAdd(&s_colsum[48 + b + 2], cs3.z); atomicAdd(&s_colsum[48 + b + 3], cs3.w);
    }
    __syncthreads();

    if (tid < KC) {
        atomicAdd(&ws[tid],       s_colsum[tid]);
        atomicAdd(&ws[64 + tid],  s_dist[tid]);
        atomicAdd(&ws[128 + tid], s_cnt[tid]);
    }
}

// one block per center row i; thread j computes ||c_i - c_j|| (j != i)
__global__ void aux_sep(const float* __restrict__ centers, float* __restrict__ ws)
{
    __shared__ float rowi[DD];
    const int i = blockIdx.x;
    const int j = threadIdx.x;

    if (j < 16) ((float4*)rowi)[j] = ((const float4*)(centers + (size_t)i * DD))[j];
    __syncthreads();

    float ss = 0.f;
    const float4* cj = (const float4*)(centers + (size_t)j * DD);
    #pragma unroll
    for (int q = 0; q < 16; q++) {
        float4 u = cj[q];
        float e0 = u.x - rowi[q*4+0], e1 = u.y - rowi[q*4+1];
        float e2 = u.z - rowi[q*4+2], e3 = u.w - rowi[q*4+3];
        ss += e0*e0 + e1*e1 + e2*e2 + e3*e3;
    }
    float dist = (i != j && ss > 0.f) ? sqrtf(ss) : 0.f;

    #pragma unroll
    for (int d = 1; d < 64; d <<= 1) dist += __shfl_xor(dist, d, 64);
    if (j == 0) atomicAdd(&ws[192], dist);
}

__global__ void aux_fin(const float* __restrict__ ws, float* __restrict__ out, int B)
{
    const int k = threadIdx.x;  // 64 threads
    const float uni = 1.0f / 64.0f;

    float p   = ws[k] / (float)B;
    float bal = uni * (logf(uni) - logf(p + 1e-8f));

    float cnt = ws[128 + k];
    float ne  = cnt > 0.f ? 1.f : 0.f;
    float pcm = ne * (ws[64 + k] / fmaxf(cnt, 1.f));
    float ps  = p;

    #pragma unroll
    for (int d = 1; d < 64; d <<= 1) {
        bal += __shfl_xor(bal, d, 64);
        ne  += __shfl_xor(ne,  d, 64);
        pcm += __shfl_xor(pcm, d, 64);
        ps  += __shfl_xor(ps,  d, 64);
    }

    float comp = pcm / fmaxf(ne, 1.f);
    float pm   = ps * (1.0f / 64.0f);
    float dv   = (p - pm) * (p - pm);
    #pragma unroll
    for (int d = 1; d < 64; d <<= 1) dv += __shfl_xor(dv, d, 64);
    float stdv = sqrtf(dv / 63.0f);

    float sep = -ws[192] / (64.0f * 63.0f);

    if (k == 0) {
        out[0] = 0.1f * bal + 0.1f * sep + 0.1f * comp;
        out[1] = bal;
        out[2] = sep;
        out[3] = comp;
        out[4] = stdv;
    }
}

extern "C" void kernel_launch(void* const* d_in, const int* in_sizes, int n_in,
                              void* d_out, int out_size, void* d_ws, size_t ws_size,
                              hipStream_t stream) {
    const float* z       = (const float*)d_in[0];
    const float* assign  = (const float*)d_in[1];
    const float* centers = (const float*)d_in[2];
    float* ws = (float*)d_ws;
    const int B = in_sizes[0] / DD;

    hipMemsetAsync(d_ws, 0, 1024, stream);
    aux_sep<<<64, 64, 0, stream>>>(centers, ws);
    aux_main<<<1024, 256, 0, stream>>>(z, assign, centers, ws, B);
    aux_fin<<<1, 64, 0, stream>>>(ws, (float*)d_out, B);
}